// Round 24
// baseline (33.050 us; speedup 1.0000x reference)
//
#include <hip/hip_runtime.h>

// SplineConv as skinny-K GEMM: out[n,oi] = sum_k W[n,k] * CT[k,oi].
// M=32768 points, N=1024 channels, K=64. f16 MFMA 16x16x32, f32 acc.
//
// Round-24 = round-23 (31.6us, write-back CONFIRMED +7% post-swizzle) + R21's
// Wp LDS-staging, RE-TESTED in the new regime. R21 was null under nt stores
// (store-queue-bound -> load stalls masked). Under write-back the store path
// drains at fabric rate, exposing the in-loop Wp loads (prefetch-1 ~250cy vs
// cross-XCD L3 ~500+cy). Staging: 4 coalesced dwordx4/thread upfront, one
// barrier, loop B-frags via conflict-free ds_read_b128 -> ZERO in-loop
// global loads.
//  - T1 XCD swizzle (+8% confirmed), wave-private XOR transpose (no barrier),
//    4 x 256B full-line plain write-back stores - unchanged from R23.
// prep_kernel identical to R13-R23 (verified, absmax 1.95e-3).

#define NPTS   32768
#define DIM    1024
#define MT     (NPTS / 16)        // 2048 point-tiles
#define WELEM  (MT * 2 * 64 * 8)  // W_perm f16 elements (4 MiB)

typedef _Float16 f16x8 __attribute__((ext_vector_type(8)));
typedef float    f32x4 __attribute__((ext_vector_type(4)));

__device__ __forceinline__ float safe_div(float n, float d) {
    return (d == 0.0f) ? n : (n / d);
}

__device__ __forceinline__ void span_weights(float v, const float* __restrict__ T,
                                             int& k, float& w0, float& w1, float& w2) {
    float t3 = T[3], t4 = T[4], t5 = T[5], t6 = T[6];
    k = 2 + (v >= t3) + (v >= t4) + (v >= t5) + (v >= t6);
    float Tm1 = T[k - 1], T0 = T[k], Tp1 = T[k + 1], Tp2 = T[k + 2];
    float a10 = safe_div(v - Tm1, Tp1 - Tm1);
    float a11 = safe_div(v - T0,  Tp2 - T0);
    float a21 = safe_div(v - T0,  Tp1 - T0);
    w0 = (1.0f - a21) * (1.0f - a10);
    w1 = (1.0f - a21) * a10 + a21 * (1.0f - a11);
    w2 = a21 * a11;
}

__global__ __launch_bounds__(256) void prep_kernel(
    const float* __restrict__ xy,
    const float* __restrict__ Tx,
    const float* __restrict__ Ty,
    const float* __restrict__ C,
    _Float16* __restrict__ Wp,
    _Float16* __restrict__ Cp)
{
    const int b = blockIdx.x;
    const int t = threadIdx.x;
    if (b < MT / 2) {
        // ---- W_perm: one thread per (point-tile, k-step, lane) 16B record ----
        const int id   = b * 256 + t;          // 0 .. 262143
        const int lane = id & 63;
        const int step = (id >> 6) & 1;
        const int tile = id >> 7;
        const int n    = tile * 16 + (lane & 15);   // B col = lane%16
        const int g    = lane >> 4;                  // k-group

        const float2 pt = ((const float2*)xy)[n];
        int kx, ky;
        float wx0, wx1, wx2, wy0, wy1, wy2;
        span_weights(pt.x, Tx, kx, wx0, wx1, wx2);
        span_weights(pt.y, Ty, ky, wy0, wy1, wy2);
        const int off = (kx - 2) * 7 + (ky - 2);

        f16x8 frag;
#pragma unroll
        for (int j = 0; j < 8; ++j) {
            const int k   = step * 32 + g * 8 + j;
            const int rel = k - off;
            const float va = (rel >= 14) ? wx2 : ((rel >= 7) ? wx1 : wx0);
            const int   bb = rel - ((rel >= 14) ? 14 : ((rel >= 7) ? 7 : 0));
            const float vb = (bb == 0) ? wy0 : ((bb == 1) ? wy1 : wy2);
            const bool valid = (rel >= 0) && (rel <= 16) && (bb >= 0) && (bb <= 2);
            frag[j] = (_Float16)(valid ? va * vb : 0.0f);
        }
        *(f16x8*)(Wp + (size_t)id * 8) = frag;
    } else if (b < MT / 2 + 32) {
        // ---- C_perm: C[ch][k] in A-fragment order (row=ch, k-grouped) ----
        const int id    = (b - MT / 2) * 256 + t;   // 0 .. 8191
        const int lane  = id & 63;
        const int step  = (id >> 6) & 1;
        const int ctile = id >> 7;
        const int ch    = ctile * 16 + (lane & 15); // A row = lane%16
        const int g     = lane >> 4;

        f16x8 frag;
#pragma unroll
        for (int j = 0; j < 8; ++j) {
            const int k = step * 32 + g * 8 + j;
            frag[j] = (_Float16)((k < 49) ? C[(size_t)ch * 49 + k] : 0.0f);
        }
        *(f16x8*)(Cp + (size_t)id * 8) = frag;
    }
}

__global__ __launch_bounds__(256, 4) void spline_mfma_kernel(
    const _Float16* __restrict__ Wp,
    const _Float16* __restrict__ Cp,
    float* __restrict__ out)
{
    __shared__ _Float16 wlds[8 * 2 * 64 * 8];  // 16 KiB: block's Wp slice
    __shared__ float    tbuf[4][1024];         // 16 KiB: wave-private transpose

    const int t    = threadIdx.x;
    const int lane = t & 63;
    const int w    = t >> 6;                   // wave 0..3

    // --- T1 XCD swizzle (confirmed +8%): contiguous output per XCD. ---
    const int bid    = blockIdx.x;
    const int swz    = ((bid & 7) << 7) | (bid >> 3);
    const int chgrp  = swz & 3;                // 256-channel group
    const int pchunk = swz >> 2;               // 8 point-tile chunk (128 points)

    // --- Stage this block's contiguous 16 KiB Wp slice into LDS: 4 coalesced
    // dwordx4 per thread, issued before the A-frag loads. One barrier. ---
    {
        const f16x8* src = (const f16x8*)(Wp + (size_t)pchunk * (8 * 2 * 64 * 8));
        f16x8* dst = (f16x8*)wlds;
#pragma unroll
        for (int i = 0; i < 4; ++i)
            dst[t + i * 256] = src[t + i * 256];
    }

    // A-fragments: this wave's 4 channel-tiles x 2 k-steps (register-resident;
    // Cp is 128 KiB -> L2-hot for every block).
    f16x8 af[4][2];
#pragma unroll
    for (int ct = 0; ct < 4; ++ct)
#pragma unroll
        for (int st = 0; st < 2; ++st) {
            const int ctg = chgrp * 16 + w * 4 + ct;
            af[ct][st] = *(const f16x8*)(Cp + ((size_t)(ctg * 2 + st) * 64 + lane) * 8);
        }

    __syncthreads();

    const int p  = lane & 15;                  // D col = point within tile
    const int h  = lane >> 4;                  // D row group
    const int cb = lane & 15;                  // read-back granule index
    float* const wbuf = &tbuf[w][0];

#pragma unroll
    for (int pt = 0; pt < 8; ++pt) {
        const int ptile = pchunk * 8 + pt;

        // B-fragments from LDS (conflict-free lane*16B ds_read_b128).
        const f16x8 b0 = *(const f16x8*)&wlds[(size_t)((pt * 2 + 0) * 64 + lane) * 8];
        const f16x8 b1 = *(const f16x8*)&wlds[(size_t)((pt * 2 + 1) * 64 + lane) * 8];

        f32x4 acc[4];
#pragma unroll
        for (int ct = 0; ct < 4; ++ct) {
            f32x4 z; z[0] = 0.0f; z[1] = 0.0f; z[2] = 0.0f; z[3] = 0.0f;
            acc[ct] = __builtin_amdgcn_mfma_f32_16x16x32_f16(af[ct][0], b0, z, 0, 0, 0);
        }
#pragma unroll
        for (int ct = 0; ct < 4; ++ct)
            acc[ct] = __builtin_amdgcn_mfma_f32_16x16x32_f16(af[ct][1], b1, acc[ct], 0, 0, 0);

        // --- Wave-private LDS transpose (no barrier), XOR granule swizzle. ---
#pragma unroll
        for (int ct = 0; ct < 4; ++ct) {
            const int g16 = ct * 4 + h;
            const int col = (g16 & 8) | ((g16 ^ p) & 7);
            *(f32x4*)(wbuf + p * 64 + (col << 2)) = acc[ct];
        }

        // --- Read back + store: instr gg covers points gg*4..gg*4+3, each as
        // 16 lanes x 16B = 256B contiguous (2 full 128B lines). Plain
        // write-back stores (L3 absorbs the contiguous per-XCD stream). ---
#pragma unroll
        for (int gg = 0; gg < 4; ++gg) {
            const int pr  = gg * 4 + h;
            const int col = (cb & 8) | ((cb ^ pr) & 7);
            f32x4 v = *(const f32x4*)(wbuf + pr * 64 + (col << 2));
            float* dst = out + (size_t)(ptile * 16 + pr) * DIM
                             + chgrp * 256 + w * 64 + cb * 4;
            *(f32x4*)dst = v;
        }
    }
}

extern "C" void kernel_launch(void* const* d_in, const int* in_sizes, int n_in,
                              void* d_out, int out_size, void* d_ws, size_t ws_size,
                              hipStream_t stream) {
    const float* xy = (const float*)d_in[0];
    const float* Tx = (const float*)d_in[1];
    const float* Ty = (const float*)d_in[2];
    const float* C  = (const float*)d_in[3];
    float* out = (float*)d_out;

    _Float16* Wp = (_Float16*)d_ws;            // 4 MiB
    _Float16* Cp = Wp + WELEM;                 // 128 KiB

    prep_kernel<<<MT / 2 + 32, 256, 0, stream>>>(xy, Tx, Ty, C, Wp, Cp);
    spline_mfma_kernel<<<4 * (MT / 8), 256, 0, stream>>>(Wp, Cp, out);
}

// Round 25
// 32.435 us; speedup vs baseline: 1.0190x; 1.0190x over previous
//
#include <hip/hip_runtime.h>

// SplineConv as skinny-K GEMM: out[n,oi] = sum_k W[n,k] * CT[k,oi].
// M=32768 points, N=1024 channels, K=64. f16 MFMA 16x16x32, f32 acc.
//
// Round-25 = round-23 (31.6us, best) with ONE change: the LDS transpose is
// REMOVED and acc stored directly (R14 addressing). The transpose was built
// for the nt-store regime where 64B segments = half-line HBM transactions;
// under write-back the sectored L2 merges the h-group segments into full
// dirty lines, so the transpose's loop cost (8 ds_b128/iter ~96cy/wave-iter
// + ds_write->ds_read dependency before store issue) is pure overhead.
//  - Direct store: lane's acc[ct] = 4 consecutive channels of point p ->
//    one f32x4 per ct; 16 x 64B segments/instr, all within the XCD's
//    contiguous post-swizzle slice (L2-merged).
//  - T1 XCD swizzle (+8% confirmed), plain write-back stores (+7% confirmed),
//    Wp prefetch-1 — unchanged from R23. No LDS, no barriers in main at all.
// prep_kernel identical to R13-R24 (verified, absmax 1.95e-3).

#define NPTS   32768
#define DIM    1024
#define MT     (NPTS / 16)        // 2048 point-tiles
#define WELEM  (MT * 2 * 64 * 8)  // W_perm f16 elements (4 MiB)

typedef _Float16 f16x8 __attribute__((ext_vector_type(8)));
typedef float    f32x4 __attribute__((ext_vector_type(4)));

__device__ __forceinline__ float safe_div(float n, float d) {
    return (d == 0.0f) ? n : (n / d);
}

__device__ __forceinline__ void span_weights(float v, const float* __restrict__ T,
                                             int& k, float& w0, float& w1, float& w2) {
    float t3 = T[3], t4 = T[4], t5 = T[5], t6 = T[6];
    k = 2 + (v >= t3) + (v >= t4) + (v >= t5) + (v >= t6);
    float Tm1 = T[k - 1], T0 = T[k], Tp1 = T[k + 1], Tp2 = T[k + 2];
    float a10 = safe_div(v - Tm1, Tp1 - Tm1);
    float a11 = safe_div(v - T0,  Tp2 - T0);
    float a21 = safe_div(v - T0,  Tp1 - T0);
    w0 = (1.0f - a21) * (1.0f - a10);
    w1 = (1.0f - a21) * a10 + a21 * (1.0f - a11);
    w2 = a21 * a11;
}

__global__ __launch_bounds__(256) void prep_kernel(
    const float* __restrict__ xy,
    const float* __restrict__ Tx,
    const float* __restrict__ Ty,
    const float* __restrict__ C,
    _Float16* __restrict__ Wp,
    _Float16* __restrict__ Cp)
{
    const int b = blockIdx.x;
    const int t = threadIdx.x;
    if (b < MT / 2) {
        // ---- W_perm: one thread per (point-tile, k-step, lane) 16B record ----
        const int id   = b * 256 + t;          // 0 .. 262143
        const int lane = id & 63;
        const int step = (id >> 6) & 1;
        const int tile = id >> 7;
        const int n    = tile * 16 + (lane & 15);   // B col = lane%16
        const int g    = lane >> 4;                  // k-group

        const float2 pt = ((const float2*)xy)[n];
        int kx, ky;
        float wx0, wx1, wx2, wy0, wy1, wy2;
        span_weights(pt.x, Tx, kx, wx0, wx1, wx2);
        span_weights(pt.y, Ty, ky, wy0, wy1, wy2);
        const int off = (kx - 2) * 7 + (ky - 2);

        f16x8 frag;
#pragma unroll
        for (int j = 0; j < 8; ++j) {
            const int k   = step * 32 + g * 8 + j;
            const int rel = k - off;
            const float va = (rel >= 14) ? wx2 : ((rel >= 7) ? wx1 : wx0);
            const int   bb = rel - ((rel >= 14) ? 14 : ((rel >= 7) ? 7 : 0));
            const float vb = (bb == 0) ? wy0 : ((bb == 1) ? wy1 : wy2);
            const bool valid = (rel >= 0) && (rel <= 16) && (bb >= 0) && (bb <= 2);
            frag[j] = (_Float16)(valid ? va * vb : 0.0f);
        }
        *(f16x8*)(Wp + (size_t)id * 8) = frag;
    } else if (b < MT / 2 + 32) {
        // ---- C_perm: C[ch][k] in A-fragment order (row=ch, k-grouped) ----
        const int id    = (b - MT / 2) * 256 + t;   // 0 .. 8191
        const int lane  = id & 63;
        const int step  = (id >> 6) & 1;
        const int ctile = id >> 7;
        const int ch    = ctile * 16 + (lane & 15); // A row = lane%16
        const int g     = lane >> 4;

        f16x8 frag;
#pragma unroll
        for (int j = 0; j < 8; ++j) {
            const int k = step * 32 + g * 8 + j;
            frag[j] = (_Float16)((k < 49) ? C[(size_t)ch * 49 + k] : 0.0f);
        }
        *(f16x8*)(Cp + (size_t)id * 8) = frag;
    }
}

__global__ __launch_bounds__(256, 4) void spline_mfma_kernel(
    const _Float16* __restrict__ Wp,
    const _Float16* __restrict__ Cp,
    float* __restrict__ out)
{
    const int t    = threadIdx.x;
    const int lane = t & 63;
    const int w    = t >> 6;                   // wave 0..3

    // --- T1 XCD swizzle (confirmed +8%): contiguous output per XCD. ---
    const int bid    = blockIdx.x;
    const int swz    = ((bid & 7) << 7) | (bid >> 3);
    const int chgrp  = swz & 3;                // 256-channel group
    const int pchunk = swz >> 2;               // 8 point-tile chunk (128 points)

    // A-fragments: this wave's 4 channel-tiles x 2 k-steps (register-resident;
    // Cp is 128 KiB -> L2-hot for every block).
    f16x8 af[4][2];
#pragma unroll
    for (int ct = 0; ct < 4; ++ct)
#pragma unroll
        for (int st = 0; st < 2; ++st) {
            const int ctg = chgrp * 16 + w * 4 + ct;
            af[ct][st] = *(const f16x8*)(Cp + ((size_t)(ctg * 2 + st) * 64 + lane) * 8);
        }

    const int p = lane & 15;                   // D col = point within tile
    const int h = lane >> 4;                   // D row group

    // Prefetch first tile's B-fragments.
    const int ptile0 = pchunk * 8;
    f16x8 nb0 = *(const f16x8*)(Wp + ((size_t)(ptile0 * 2 + 0) * 64 + lane) * 8);
    f16x8 nb1 = *(const f16x8*)(Wp + ((size_t)(ptile0 * 2 + 1) * 64 + lane) * 8);

#pragma unroll
    for (int pt = 0; pt < 8; ++pt) {
        const int ptile = pchunk * 8 + pt;
        const f16x8 b0 = nb0;
        const f16x8 b1 = nb1;
        if (pt + 1 < 8) {   // issue next tile's loads BEFORE this tile's stores
            nb0 = *(const f16x8*)(Wp + ((size_t)((ptile + 1) * 2 + 0) * 64 + lane) * 8);
            nb1 = *(const f16x8*)(Wp + ((size_t)((ptile + 1) * 2 + 1) * 64 + lane) * 8);
        }

        f32x4 acc[4];
#pragma unroll
        for (int ct = 0; ct < 4; ++ct) {
            f32x4 z; z[0] = 0.0f; z[1] = 0.0f; z[2] = 0.0f; z[3] = 0.0f;
            acc[ct] = __builtin_amdgcn_mfma_f32_16x16x32_f16(af[ct][0], b0, z, 0, 0, 0);
        }
#pragma unroll
        for (int ct = 0; ct < 4; ++ct)
            acc[ct] = __builtin_amdgcn_mfma_f32_16x16x32_f16(af[ct][1], b1, acc[ct], 0, 0, 0);

        // --- Direct store (no LDS transpose): lane's acc[ct] = channels
        // (chgrp*16+w*4+ct)*16 + h*4 .. +3 of point ptile*16+p -> one f32x4.
        // 16 x 64B segments per instr, merged by the sectored L2 within the
        // XCD's contiguous post-swizzle slice. Plain write-back. ---
        float* prow = out + (size_t)(ptile * 16 + p) * DIM
                          + (chgrp * 16 + w * 4) * 16 + h * 4;
#pragma unroll
        for (int ct = 0; ct < 4; ++ct)
            *(f32x4*)(prow + ct * 16) = acc[ct];
    }
}

extern "C" void kernel_launch(void* const* d_in, const int* in_sizes, int n_in,
                              void* d_out, int out_size, void* d_ws, size_t ws_size,
                              hipStream_t stream) {
    const float* xy = (const float*)d_in[0];
    const float* Tx = (const float*)d_in[1];
    const float* Ty = (const float*)d_in[2];
    const float* C  = (const float*)d_in[3];
    float* out = (float*)d_out;

    _Float16* Wp = (_Float16*)d_ws;            // 4 MiB
    _Float16* Cp = Wp + WELEM;                 // 128 KiB

    prep_kernel<<<MT / 2 + 32, 256, 0, stream>>>(xy, Tx, Ty, C, Wp, Cp);
    spline_mfma_kernel<<<4 * (MT / 8), 256, 0, stream>>>(Wp, Cp, out);
}

// Round 26
// 32.120 us; speedup vs baseline: 1.0290x; 1.0098x over previous
//
#include <hip/hip_runtime.h>

// SplineConv as skinny-K GEMM: out[n,oi] = sum_k W[n,k] * CT[k,oi].
// M=32768 points, N=1024 channels, K=64. f16 MFMA 16x16x32, f32 acc.
//
// Round-26 = segment-size curve completion: R19's block-cooperative transpose
// (full 1KiB lane-contiguous store instructions) + the two CONFIRMED levers,
// T1 XCD swizzle (+8%) and plain write-back stores (+7%). Under write-back:
// 64B segments (R25) = 32.4us, 256B (R23) = 31.6us -> testing 1KiB.
// Barrier cost of the block transpose measured null (R19 vs R20); pre-barrier
// vmcnt(0) drain is cheap under write-back (stores retire into L2, not HBM).
//  - Block transpose: 16 pts x 256 ch (16KiB), double-buffered (32KiB),
//    1 barrier/iter; wave w stores points 4w..4w+3 as 64-lane x 16B = 1KiB.
//  - XOR swizzle ci^((p&7)<<2): conflict-free both directions.
// prep_kernel identical to R13-R25 (verified, absmax 1.95e-3).

#define NPTS   32768
#define DIM    1024
#define MT     (NPTS / 16)        // 2048 point-tiles
#define WELEM  (MT * 2 * 64 * 8)  // W_perm f16 elements (4 MiB)

typedef _Float16 f16x8 __attribute__((ext_vector_type(8)));
typedef float    f32x4 __attribute__((ext_vector_type(4)));

__device__ __forceinline__ float safe_div(float n, float d) {
    return (d == 0.0f) ? n : (n / d);
}

__device__ __forceinline__ void span_weights(float v, const float* __restrict__ T,
                                             int& k, float& w0, float& w1, float& w2) {
    float t3 = T[3], t4 = T[4], t5 = T[5], t6 = T[6];
    k = 2 + (v >= t3) + (v >= t4) + (v >= t5) + (v >= t6);
    float Tm1 = T[k - 1], T0 = T[k], Tp1 = T[k + 1], Tp2 = T[k + 2];
    float a10 = safe_div(v - Tm1, Tp1 - Tm1);
    float a11 = safe_div(v - T0,  Tp2 - T0);
    float a21 = safe_div(v - T0,  Tp1 - T0);
    w0 = (1.0f - a21) * (1.0f - a10);
    w1 = (1.0f - a21) * a10 + a21 * (1.0f - a11);
    w2 = a21 * a11;
}

__global__ __launch_bounds__(256) void prep_kernel(
    const float* __restrict__ xy,
    const float* __restrict__ Tx,
    const float* __restrict__ Ty,
    const float* __restrict__ C,
    _Float16* __restrict__ Wp,
    _Float16* __restrict__ Cp)
{
    const int b = blockIdx.x;
    const int t = threadIdx.x;
    if (b < MT / 2) {
        // ---- W_perm: one thread per (point-tile, k-step, lane) 16B record ----
        const int id   = b * 256 + t;          // 0 .. 262143
        const int lane = id & 63;
        const int step = (id >> 6) & 1;
        const int tile = id >> 7;
        const int n    = tile * 16 + (lane & 15);   // B col = lane%16
        const int g    = lane >> 4;                  // k-group

        const float2 pt = ((const float2*)xy)[n];
        int kx, ky;
        float wx0, wx1, wx2, wy0, wy1, wy2;
        span_weights(pt.x, Tx, kx, wx0, wx1, wx2);
        span_weights(pt.y, Ty, ky, wy0, wy1, wy2);
        const int off = (kx - 2) * 7 + (ky - 2);

        f16x8 frag;
#pragma unroll
        for (int j = 0; j < 8; ++j) {
            const int k   = step * 32 + g * 8 + j;
            const int rel = k - off;
            const float va = (rel >= 14) ? wx2 : ((rel >= 7) ? wx1 : wx0);
            const int   bb = rel - ((rel >= 14) ? 14 : ((rel >= 7) ? 7 : 0));
            const float vb = (bb == 0) ? wy0 : ((bb == 1) ? wy1 : wy2);
            const bool valid = (rel >= 0) && (rel <= 16) && (bb >= 0) && (bb <= 2);
            frag[j] = (_Float16)(valid ? va * vb : 0.0f);
        }
        *(f16x8*)(Wp + (size_t)id * 8) = frag;
    } else if (b < MT / 2 + 32) {
        // ---- C_perm: C[ch][k] in A-fragment order (row=ch, k-grouped) ----
        const int id    = (b - MT / 2) * 256 + t;   // 0 .. 8191
        const int lane  = id & 63;
        const int step  = (id >> 6) & 1;
        const int ctile = id >> 7;
        const int ch    = ctile * 16 + (lane & 15); // A row = lane%16
        const int g     = lane >> 4;

        f16x8 frag;
#pragma unroll
        for (int j = 0; j < 8; ++j) {
            const int k = step * 32 + g * 8 + j;
            frag[j] = (_Float16)((k < 49) ? C[(size_t)ch * 49 + k] : 0.0f);
        }
        *(f16x8*)(Cp + (size_t)id * 8) = frag;
    }
}

__global__ __launch_bounds__(256, 4) void spline_mfma_kernel(
    const _Float16* __restrict__ Wp,
    const _Float16* __restrict__ Cp,
    float* __restrict__ out)
{
    __shared__ float lds[2][16 * 256];         // 32 KiB double buffer

    const int t    = threadIdx.x;
    const int lane = t & 63;
    const int w    = t >> 6;                   // wave 0..3

    // --- T1 XCD swizzle (confirmed +8%): contiguous output per XCD. ---
    const int bid    = blockIdx.x;
    const int swz    = ((bid & 7) << 7) | (bid >> 3);
    const int chgrp  = swz & 3;                // 256-channel group
    const int pchunk = swz >> 2;               // 8 point-tile chunk (128 points)

    // A-fragments: this wave's 4 channel-tiles x 2 k-steps (register-resident;
    // Cp is 128 KiB -> L2-hot for every block).
    f16x8 af[4][2];
#pragma unroll
    for (int ct = 0; ct < 4; ++ct)
#pragma unroll
        for (int st = 0; st < 2; ++st) {
            const int ctg = chgrp * 16 + w * 4 + ct;
            af[ct][st] = *(const f16x8*)(Cp + ((size_t)(ctg * 2 + st) * 64 + lane) * 8);
        }

    const int p = lane & 15;                   // D col = point within tile
    const int h = lane >> 4;                   // D row group

#pragma unroll
    for (int pt = 0; pt < 8; ++pt) {
        const int ptile = pchunk * 8 + pt;
        const f16x8 b0 = *(const f16x8*)(Wp + ((size_t)(ptile * 2 + 0) * 64 + lane) * 8);
        const f16x8 b1 = *(const f16x8*)(Wp + ((size_t)(ptile * 2 + 1) * 64 + lane) * 8);

        f32x4 acc[4];
#pragma unroll
        for (int ct = 0; ct < 4; ++ct) {
            f32x4 z; z[0] = 0.0f; z[1] = 0.0f; z[2] = 0.0f; z[3] = 0.0f;
            acc[ct] = __builtin_amdgcn_mfma_f32_16x16x32_f16(af[ct][0], b0, z, 0, 0, 0);
        }
#pragma unroll
        for (int ct = 0; ct < 4; ++ct)
            acc[ct] = __builtin_amdgcn_mfma_f32_16x16x32_f16(af[ct][1], b1, acc[ct], 0, 0, 0);

        // --- Block-level LDS transpose: acc[ct] = channels (w*64+ct*16+h*4..+4)
        // of point p within the block's 256-channel slice. XOR-swizzled. ---
        float* buf = lds[pt & 1];
#pragma unroll
        for (int ct = 0; ct < 4; ++ct) {
            const int ci = w * 64 + ct * 16 + h * 4;
            *(f32x4*)(buf + p * 256 + (ci ^ ((p & 7) << 2))) = acc[ct];
        }
        __syncthreads();

        // --- Cooperative store: wave w emits points 4w..4w+3, each as one
        // 64-lane x 16B contiguous 1KiB full-line PLAIN write-back store
        // (L3 absorbs the contiguous per-XCD stream at fabric rate). ---
#pragma unroll
        for (int r = 0; r < 4; ++r) {
            const int pr = 4 * w + r;
            const int ci = lane * 4;
            f32x4 v = *(const f32x4*)(buf + pr * 256 + (ci ^ ((pr & 7) << 2)));
            float* dst = out + (size_t)(ptile * 16 + pr) * DIM + chgrp * 256 + ci;
            *(f32x4*)dst = v;
        }
        // Double buffer: next iter writes lds[(pt+1)&1]; slowest wave can still
        // be reading lds[pt&1] -> no second barrier needed.
    }
}

extern "C" void kernel_launch(void* const* d_in, const int* in_sizes, int n_in,
                              void* d_out, int out_size, void* d_ws, size_t ws_size,
                              hipStream_t stream) {
    const float* xy = (const float*)d_in[0];
    const float* Tx = (const float*)d_in[1];
    const float* Ty = (const float*)d_in[2];
    const float* C  = (const float*)d_in[3];
    float* out = (float*)d_out;

    _Float16* Wp = (_Float16*)d_ws;            // 4 MiB
    _Float16* Cp = Wp + WELEM;                 // 128 KiB

    prep_kernel<<<MT / 2 + 32, 256, 0, stream>>>(xy, Tx, Ty, C, Wp, Cp);
    spline_mfma_kernel<<<4 * (MT / 8), 256, 0, stream>>>(Wp, Cp, out);
}